// Round 4
// baseline (12.764 us; speedup 1.0000x reference)
//
#include <hip/hip_runtime.h>
#include <math.h>

#define DIM 4096
#define BATCH 8192
#define NT 1024
#define NWAVES (NT / 64)
#define RPT (BATCH / NT)   // betas per thread = 8

// Single-block fused kernel, histogram formulation (no random gathers):
//   cnt_j = #{b: K_b > j},  slk_j = sum_{K_b > j} log K_b
//   n_I  = sum_j g_j cnt_j
//   ixt  = sum_j g_j slk_j - sum_j g_j log(j+1) cnt_j
//   S_l  = sum_j g_j log(lam_j) cnt_j,  S_l1 = sum_j g_j log(1-lam_j) cnt_j
// Histogram: one u64 LDS bin per K (hi=count, lo=sum(logK*2^14), exact ints ->
// deterministic). Suffix sums via reversed-index integer block scan; dot
// products fully in-register (thread owns the same reversed j's).
__global__ __launch_bounds__(NT)
void calc_kernel(const float* __restrict__ betas,
                 const float* __restrict__ lambdas,
                 const float* __restrict__ gammas,
                 float* __restrict__ out)
{
    __shared__ unsigned long long hbin[DIM];   // 32 KB
    __shared__ uint2 wtot[NWAVES];
    __shared__ float red[5][NWAVES];

    const int t = threadIdx.x;
    const int lane = t & 63;
    const int wave = t >> 6;
    const int jb = DIM - 4 - 4 * t;    // reversed ownership: scan slot i <-> j = jb+3-i

    // ---- all global loads up front ----
    const float4 la4 = *reinterpret_cast<const float4*>(lambdas + jb);
    const float4 ga4 = *reinterpret_cast<const float4*>(gammas + jb);
    const float4* b4p = reinterpret_cast<const float4*>(betas);
    const float4 bv0 = b4p[t];
    const float4 bv1 = b4p[NT + t];

    // ---- zero histogram (each thread 32 B) ----
    uint4* hz = reinterpret_cast<uint4*>(hbin);
    hz[2 * t]     = make_uint4(0u, 0u, 0u, 0u);
    hz[2 * t + 1] = make_uint4(0u, 0u, 0u, 0u);

    // ---- per-beta K + packed increment (exact f32 op sequence for floor) ----
    float bet[RPT] = { bv0.x, bv0.y, bv0.z, bv0.w, bv1.x, bv1.y, bv1.z, bv1.w };
    unsigned long long incv[RPT];
    int K[RPT];
    #pragma unroll
    for (int r = 0; r < RPT; ++r) {
        float beta = bet[r];
        float lamb = 1.0f - 1.0f / beta;          // IEEE divides: floor fidelity
        float kf   = 1.0f / (1.0f - lamb) - 1.0f;
        int k = (int)floorf(kf);
        k = min(max(k, 1), DIM - 1);
        K[r] = k;
        unsigned int lkfix = __float2uint_rn(__logf((float)k) * 16384.0f);
        incv[r] = (1ull << 32) | (unsigned long long)lkfix;
    }

    // ---- per-slot series values (independent of histogram; fills latency) ----
    // slot i <-> j = jb+3-i, so la4.w is slot 0 ... la4.x is slot 3
    float lam_s[4] = { la4.w, la4.z, la4.y, la4.x };
    float gam_s[4] = { ga4.w, ga4.z, ga4.y, ga4.x };
    float e_g[4], e_gl[4], e_gA[4], e_gB[4];
    #pragma unroll
    for (int i = 0; i < 4; ++i) {
        int j = jb + 3 - i;
        float g = gam_s[i];
        e_g[i]  = g;
        e_gl[i] = g * __logf((float)(j + 1));
        e_gA[i] = g * __logf(lam_s[i]);
        e_gB[i] = g * __logf(1.0f - lam_s[i]);   // lam in (0.05,0.95): safe
    }

    __syncthreads();   // zeroing visible

    // ---- histogram: one u64 atomic per beta ----
    #pragma unroll
    for (int r = 0; r < RPT; ++r)
        atomicAdd(&hbin[K[r]], incv[r]);

    __syncthreads();   // histogram complete

    // ---- read own 4 bins (contiguous 32 B, conflict-free pattern) ----
    const uint4 q0 = *reinterpret_cast<const uint4*>(&hbin[jb]);      // bins jb, jb+1
    const uint4 q1 = *reinterpret_cast<const uint4*>(&hbin[jb + 2]);  // bins jb+2, jb+3
    // slot0 = bin jb+3 (lo=q1.z hi=q1.w), slot1 = jb+2, slot2 = jb+1, slot3 = jb
    unsigned int cnt_s[4] = { q1.w, q1.y, q0.w, q0.y };
    unsigned int lk_s[4]  = { q1.z, q1.x, q0.z, q0.x };

    unsigned int tc = cnt_s[0] + cnt_s[1] + cnt_s[2] + cnt_s[3];
    unsigned int tl = lk_s[0] + lk_s[1] + lk_s[2] + lk_s[3];

    // ---- exact integer wave scan (width 64) of the 2 series ----
    unsigned int ic = tc, il = tl;
    #pragma unroll
    for (int off = 1; off < 64; off <<= 1) {
        unsigned int yc = __shfl_up(ic, off, 64);
        unsigned int yl = __shfl_up(il, off, 64);
        if (lane >= off) { ic += yc; il += yl; }
    }
    if (lane == 63) wtot[wave] = make_uint2(ic, il);
    __syncthreads();

    unsigned int bc = ic - tc, bl = il - tl;   // thread-exclusive base
    for (int w = 0; w < wave; ++w) {
        uint2 wt = wtot[w];
        bc += wt.x; bl += wt.y;
    }

    // ---- in-register dot products; exclusive running = suffix stats at j ----
    float a0 = 0.f, a1 = 0.f, a2 = 0.f, a3 = 0.f, a4 = 0.f;
    unsigned int rc = bc, rl = bl;
    #pragma unroll
    for (int i = 0; i < 4; ++i) {
        float cntf = (float)rc;                       // cnt_j = #{K_b > j}
        float slkf = (float)rl * (1.0f / 16384.0f);   // slk_j = sum log K_b
        a0 += e_g[i]  * slkf;   // sum g_j slk_j
        a1 += e_gl[i] * cntf;   // sum g_j log(j+1) cnt_j
        a2 += e_g[i]  * cntf;   // n_I
        a3 += e_gA[i] * cntf;   // S_lambda
        a4 += e_gB[i] * cntf;   // S_lambda_comp
        rc += cnt_s[i]; rl += lk_s[i];
    }

    // ---- reduce 5 scalars + f32 epilogue ----
    #pragma unroll
    for (int off = 32; off > 0; off >>= 1) {
        a0 += __shfl_down(a0, off, 64);
        a1 += __shfl_down(a1, off, 64);
        a2 += __shfl_down(a2, off, 64);
        a3 += __shfl_down(a3, off, 64);
        a4 += __shfl_down(a4, off, 64);
    }
    if (lane == 0) {
        red[0][wave] = a0; red[1][wave] = a1; red[2][wave] = a2;
        red[3][wave] = a3; red[4][wave] = a4;
    }
    __syncthreads();
    if (t == 0) {
        float s0 = 0.f, s1 = 0.f, s2 = 0.f, s3 = 0.f, s4 = 0.f;
        #pragma unroll
        for (int w = 0; w < NWAVES; ++w) {
            s0 += red[0][w]; s1 += red[1][w]; s2 += red[2][w];
            s3 += red[3][w]; s4 += red[4][w];
        }
        float ixt = s0 - s1;
        float nI  = s2;
        float inv_nI = 1.0f / nI;
        float gm_term  = __expf(s3 * inv_nI);
        float gm_comp  = __expf(s4 * inv_nI);
        float exp_term = __expf(2.0f * ixt * inv_nI);
        float log_term = -nI * 0.5f * __logf(gm_comp + exp_term * gm_term);
        float rhs = 1.0f - (ixt + log_term);      // IXY = 1
        float l1  = 1.0f - ixt * 0.1f;            // HX = 10
        if (l1 < 0.0f) l1 = fabsf(l1) * 20.0f;
        out[0] = rhs;
        out[1] = l1 * l1;                         // C=1, ALPHA=2
    }
}

extern "C" void kernel_launch(void* const* d_in, const int* in_sizes, int n_in,
                              void* d_out, int out_size, void* d_ws, size_t ws_size,
                              hipStream_t stream) {
    const float* betas   = (const float*)d_in[0];
    const float* lambdas = (const float*)d_in[1];
    const float* gammas  = (const float*)d_in[2];
    calc_kernel<<<1, NT, 0, stream>>>(betas, lambdas, gammas, (float*)d_out);
}